// Round 11
// baseline (218.409 us; speedup 1.0000x reference)
//
#include <hip/hip_runtime.h>
#include <math.h>

#define NFEAT 128
#define NHID  24
#define NCLS  16
#define H1DW  12                // h1 row = 24 bf16 = 12 dwords = 48B DENSE (no pad).
                                // 4.8MB footprint vs 4MB/XCD L2 (r10: -3.6us vs padded)
#define NBSH  8                 // 256 nodes per bucket
#define BKN   256
#define QSH   15                // src-quarter shift (sub-sort key for L2 phasing)
#define CAP   9216              // fixed slots per bucket (mean 8192, sigma~90: +11 sigma)
#define TILE  8192              // edges per partition tile
#define PT    1024              // partition block threads
#define EPT   (TILE / PT)       // 8 edges per thread
#define GSTR  16                // gcur stride in ints: one counter per 64B line

typedef unsigned short ushort_t;
typedef __attribute__((ext_vector_type(8))) short bf16x8_t;
typedef __attribute__((ext_vector_type(4))) float f32x4_t;

__device__ __forceinline__ ushort_t f2bf(float f) {
    unsigned x; __builtin_memcpy(&x, &f, 4);
    unsigned r = (x + 0x7FFF + ((x >> 16) & 1)) >> 16;   // RNE
    return (ushort_t)r;
}
__device__ __forceinline__ float bf2f(ushort_t h) {
    unsigned x = ((unsigned)h) << 16;
    float f; __builtin_memcpy(&f, &x, 4); return f;
}
__device__ __forceinline__ float lo_f(unsigned u) {
    unsigned x = u << 16;
    float f; __builtin_memcpy(&f, &x, 4); return f;
}
__device__ __forceinline__ float hi_f(unsigned u) {
    unsigned x = u & 0xFFFF0000u;
    float f; __builtin_memcpy(&f, &x, 4); return f;
}
__device__ __forceinline__ unsigned pack2(float a, float b) {
    return (unsigned)f2bf(a) | ((unsigned)f2bf(b) << 16);
}

// ---------------------------------------------------------------------------
// K0: one-wave W1 fragment prep (hi/lo bf16 split, prepacked) + gcur zero.
__global__ void __launch_bounds__(64) wprep_kernel(const float* __restrict__ W1,
                                                   bf16x8_t* __restrict__ wpk,
                                                   int* __restrict__ gcur) {
    int l = threadIdx.x;
    for (int i = l; i < 512; i += 64) gcur[i * GSTR] = 0;
    int mrow = l & 15;
    int kgrp = l >> 4;
#pragma unroll
    for (int ct = 0; ct < 2; ct++) {
        int n = ct * 16 + mrow;
        bool nv = (n < NHID);
#pragma unroll
        for (int kb = 0; kb < 4; kb++) {
            bf16x8_t hi, lo;
#pragma unroll
            for (int j = 0; j < 8; j++) {
                int k = kb * 32 + kgrp * 8 + j;
                float w = nv ? W1[k * NHID + n] : 0.0f;
                ushort_t h = f2bf(w);
                hi[j] = (short)h;
                lo[j] = (short)f2bf(w - bf2f(h));
            }
            int f = ct * 4 + kb;
            wpk[(f * 2 + 0) * 64 + l] = hi;
            wpk[(f * 2 + 1) * 64 + l] = lo;
        }
    }
}

// ---------------------------------------------------------------------------
// K1: LDS-staged partition into fixed-capacity bucket regions.
__global__ void __launch_bounds__(1024) part1_kernel(const int* __restrict__ ei,
                                                     int* __restrict__ gcur,
                                                     int* __restrict__ part, int E) {
    __shared__ int stage[TILE];        // 32 KB
    __shared__ ushort_t sbkt[TILE];    // 16 KB
    __shared__ int lh[512];            // hist -> cursor
    __shared__ int lofs[512];
    __shared__ int gbase[512];
    __shared__ int wsum[8];
    int t = threadIdx.x;
    int e0 = blockIdx.x * TILE;
    int cnt = min(TILE, E - e0);
    if (t < 512) lh[t] = 0;
    __syncthreads();
    int dstv[EPT];
#pragma unroll
    for (int r = 0; r < EPT; r++) {
        int i = t + r * PT;
        if (i < cnt) {
            int d = ei[e0 + i];
            dstv[r] = d;
            atomicAdd(&lh[d >> NBSH], 1);
        }
    }
    __syncthreads();
    int v = 0, s = 0;
    if (t < 512) {
        v = lh[t];
        s = v;
#pragma unroll
        for (int o = 1; o < 64; o <<= 1) {
            int u = __shfl_up(s, o, 64);
            if ((t & 63) >= o) s += u;
        }
        if ((t & 63) == 63) wsum[t >> 6] = s;
    }
    __syncthreads();
    if (t < 8) {
        int w = wsum[t];
        int ss = w;
#pragma unroll
        for (int o = 1; o < 8; o <<= 1) {
            int u = __shfl_up(ss, o, 8);
            if (t >= o) ss += u;
        }
        wsum[t] = ss - w;   // exclusive
    }
    __syncthreads();
    if (t < 512) {
        int ex = s + wsum[t >> 6] - v;
        lofs[t] = ex;
        gbase[t] = v ? (t * CAP + atomicAdd(&gcur[t * GSTR], v)) : 0;
        lh[t] = ex;   // cursor
    }
    __syncthreads();
#pragma unroll
    for (int r = 0; r < EPT; r++) {
        int i = t + r * PT;
        if (i < cnt) {
            int dst = dstv[r];
            int src = ei[E + e0 + i];
            int b = dst >> NBSH;
            int p = atomicAdd(&lh[b], 1);
            stage[p] = ((dst & (BKN - 1)) << 17) | src;
            sbkt[p] = (ushort_t)b;
        }
    }
    __syncthreads();
#pragma unroll
    for (int r = 0; r < EPT; r++) {
        int i = t + r * PT;
        if (i < cnt) {
            int b = sbkt[i];
            part[gbase[b] + (i - lofs[b])] = stage[i];
        }
    }
}

// K2: per-bucket CSR build, register-stashed single global pass. (~17.4us, r8)
__global__ void __launch_bounds__(1024) csr_kernel(const int* __restrict__ part,
                                                   const int* __restrict__ gcur,
                                                   int* __restrict__ csr,
                                                   int* __restrict__ rowst,
                                                   ushort_t* __restrict__ degs,
                                                   float* __restrict__ dinv,
                                                   int NBUCK, int N) {
    __shared__ int h[1024];
    __shared__ int cur[1024];
    __shared__ int wsum[16];
    int b = blockIdx.x, t = threadIdx.x;
    int st = b * CAP;
    int cnt = gcur[b * GSTR];          // <= CAP = 9216 = 9*1024
    h[t] = 0;
    __syncthreads();
    int r[9];
#pragma unroll
    for (int i = 0; i < 9; i++) {
        int idx = t + (i << 10);
        if (idx < cnt) {
            int ent = part[st + idx];
            r[i] = ent;
            atomicAdd(&h[((ent >> 17) << 2) | ((ent & 0x1FFFF) >> QSH)], 1);
        }
    }
    __syncthreads();
    int v = h[t];
    if ((t & 3) == 0) {
        int node = (b << NBSH) + (t >> 2);
        if (node < N) {
            int dg = h[t] + h[t + 1] + h[t + 2] + h[t + 3];
            dinv[node] = rsqrtf((float)dg + 1.0f);
            degs[node] = (ushort_t)dg;
        }
    }
    int s = v;
#pragma unroll
    for (int o = 1; o < 64; o <<= 1) {
        int u = __shfl_up(s, o, 64);
        if ((t & 63) >= o) s += u;
    }
    if ((t & 63) == 63) wsum[t >> 6] = s;
    __syncthreads();
    if (t < 16) {
        int w = wsum[t];
        int ss = w;
#pragma unroll
        for (int o = 1; o < 16; o <<= 1) {
            int u = __shfl_up(ss, o, 16);
            if (t >= o) ss += u;
        }
        wsum[t] = ss - w;
    }
    __syncthreads();
    int ex = s + wsum[t >> 6] - v;
    if ((t & 3) == 0) {
        int node = (b << NBSH) + (t >> 2);
        if (node < N) rowst[node] = st + ex;
    }
    cur[t] = ex;
    __syncthreads();
#pragma unroll
    for (int i = 0; i < 9; i++) {
        int idx = t + (i << 10);
        if (idx < cnt) {
            int ent = r[i];
            int src = ent & 0x1FFFF;
            int p = atomicAdd(&cur[((ent >> 17) << 2) | (src >> QSH)], 1);
            csr[st + p] = src;
        }
    }
}

// K3: h1(bf16, DENSE stride 24) = dinv[row] * (x @ W1), via MFMA. Prepacked
//     W1 fragments; 3-term bf16 split for f32 accuracy.
__global__ void __launch_bounds__(256) gemm1_kernel(const float* __restrict__ x,
                                                    const bf16x8_t* __restrict__ wpk,
                                                    const float* __restrict__ dinv,
                                                    unsigned* __restrict__ h1u, int N) {
    int gw = (blockIdx.x * 256 + threadIdx.x) >> 6;   // global wave id = row tile
    int l = threadIdx.x & 63;
    int ntile = (N + 15) >> 4;
    if (gw >= ntile) return;
    int mrow = l & 15;
    int kgrp = l >> 4;          // 0..3

    bf16x8_t whi[2][4], wlo[2][4];
#pragma unroll
    for (int ct = 0; ct < 2; ct++) {
#pragma unroll
        for (int kb = 0; kb < 4; kb++) {
            int f = ct * 4 + kb;
            whi[ct][kb] = wpk[(f * 2 + 0) * 64 + l];
            wlo[ct][kb] = wpk[(f * 2 + 1) * 64 + l];
        }
    }

    int row0 = gw * 16;
    int xrow = row0 + mrow;
    if (xrow >= N) xrow = N - 1;
    const float* xp = x + (size_t)xrow * NFEAT + kgrp * 8;

    f32x4_t acc0 = {0.f, 0.f, 0.f, 0.f};
    f32x4_t acc1 = {0.f, 0.f, 0.f, 0.f};
#pragma unroll
    for (int kb = 0; kb < 4; kb++) {
        float4 fa = *(const float4*)(xp + kb * 32);
        float4 fb = *(const float4*)(xp + kb * 32 + 4);
        float f[8] = {fa.x, fa.y, fa.z, fa.w, fb.x, fb.y, fb.z, fb.w};
        bf16x8_t ah, al;
#pragma unroll
        for (int j = 0; j < 8; j++) {
            ushort_t h = f2bf(f[j]);
            ah[j] = (short)h;
            al[j] = (short)f2bf(f[j] - bf2f(h));
        }
        acc0 = __builtin_amdgcn_mfma_f32_16x16x32_bf16(ah, whi[0][kb], acc0, 0, 0, 0);
        acc0 = __builtin_amdgcn_mfma_f32_16x16x32_bf16(ah, wlo[0][kb], acc0, 0, 0, 0);
        acc0 = __builtin_amdgcn_mfma_f32_16x16x32_bf16(al, whi[0][kb], acc0, 0, 0, 0);
        acc1 = __builtin_amdgcn_mfma_f32_16x16x32_bf16(ah, whi[1][kb], acc1, 0, 0, 0);
        acc1 = __builtin_amdgcn_mfma_f32_16x16x32_bf16(ah, wlo[1][kb], acc1, 0, 0, 0);
        acc1 = __builtin_amdgcn_mfma_f32_16x16x32_bf16(al, whi[1][kb], acc1, 0, 0, 0);
    }

    ushort_t* hs = (ushort_t*)h1u;
#pragma unroll
    for (int r = 0; r < 4; r++) {
        int row = row0 + kgrp * 4 + r;
        if (row < N) {
            float di = dinv[row];
            hs[(size_t)row * (2 * H1DW) + mrow] = f2bf(di * acc0[r]);
            if (mrow < NHID - 16)
                hs[(size_t)row * (2 * H1DW) + 16 + mrow] = f2bf(di * acc1[r]);
        }
    }
}

// K4: layer-1 pull aggregation + FUSED layer-2 dense transform.
//     12 lanes x 2 feats per node; dense 48B h1 rows; 16-DEEP rotated gather
//     pipeline (16 gathers in flight, next 16 csr indices prefetched) —
//     halves latency-exposure windows vs the 8-deep r3 version.
__global__ void __launch_bounds__(192) agg1_kernel(const int* __restrict__ csr,
                                                   const int* __restrict__ rowst,
                                                   const ushort_t* __restrict__ degs,
                                                   const unsigned* __restrict__ h1u,
                                                   const float* __restrict__ dinv,
                                                   const float* __restrict__ b1,
                                                   const float* __restrict__ W2,
                                                   unsigned* __restrict__ h2u, int N) {
    __shared__ float hl[16][25];          // +1 pad
    __shared__ float w2s[NHID * NCLS];
    int t = threadIdx.x;
    for (int i = t; i < NHID * NCLS; i += 192) w2s[i] = W2[i];
    int g = t / 12;
    int lane = t - g * 12;
    int node = blockIdx.x * 16 + g;
    if (node < N) {
        int st = rowst[node];
        int dg = degs[node];
        float a0x = 0.f, a0y = 0.f, a1x = 0.f, a1y = 0.f;
        float a2x = 0.f, a2y = 0.f, a3x = 0.f, a3y = 0.f;
        int e = 0;
        if (dg >= 16) {
            int s0 = csr[st + 0],  s1 = csr[st + 1];
            int s2 = csr[st + 2],  s3 = csr[st + 3];
            int s4 = csr[st + 4],  s5 = csr[st + 5];
            int s6 = csr[st + 6],  s7 = csr[st + 7];
            int s8 = csr[st + 8],  s9 = csr[st + 9];
            int sa = csr[st + 10], sb = csr[st + 11];
            int sc = csr[st + 12], sd = csr[st + 13];
            int se = csr[st + 14], sf = csr[st + 15];
            for (; e + 32 <= dg; e += 16) {
                unsigned u0 = h1u[s0 * H1DW + lane];
                unsigned u1 = h1u[s1 * H1DW + lane];
                unsigned u2 = h1u[s2 * H1DW + lane];
                unsigned u3 = h1u[s3 * H1DW + lane];
                unsigned u4 = h1u[s4 * H1DW + lane];
                unsigned u5 = h1u[s5 * H1DW + lane];
                unsigned u6 = h1u[s6 * H1DW + lane];
                unsigned u7 = h1u[s7 * H1DW + lane];
                unsigned u8 = h1u[s8 * H1DW + lane];
                unsigned u9 = h1u[s9 * H1DW + lane];
                unsigned ua = h1u[sa * H1DW + lane];
                unsigned ub = h1u[sb * H1DW + lane];
                unsigned uc = h1u[sc * H1DW + lane];
                unsigned ud = h1u[sd * H1DW + lane];
                unsigned ue = h1u[se * H1DW + lane];
                unsigned uf = h1u[sf * H1DW + lane];
                s0 = csr[st + e + 16]; s1 = csr[st + e + 17];
                s2 = csr[st + e + 18]; s3 = csr[st + e + 19];
                s4 = csr[st + e + 20]; s5 = csr[st + e + 21];
                s6 = csr[st + e + 22]; s7 = csr[st + e + 23];
                s8 = csr[st + e + 24]; s9 = csr[st + e + 25];
                sa = csr[st + e + 26]; sb = csr[st + e + 27];
                sc = csr[st + e + 28]; sd = csr[st + e + 29];
                se = csr[st + e + 30]; sf = csr[st + e + 31];
                a0x += lo_f(u0); a0y += hi_f(u0);
                a1x += lo_f(u1); a1y += hi_f(u1);
                a2x += lo_f(u2); a2y += hi_f(u2);
                a3x += lo_f(u3); a3y += hi_f(u3);
                a0x += lo_f(u4); a0y += hi_f(u4);
                a1x += lo_f(u5); a1y += hi_f(u5);
                a2x += lo_f(u6); a2y += hi_f(u6);
                a3x += lo_f(u7); a3y += hi_f(u7);
                a0x += lo_f(u8); a0y += hi_f(u8);
                a1x += lo_f(u9); a1y += hi_f(u9);
                a2x += lo_f(ua); a2y += hi_f(ua);
                a3x += lo_f(ub); a3y += hi_f(ub);
                a0x += lo_f(uc); a0y += hi_f(uc);
                a1x += lo_f(ud); a1y += hi_f(ud);
                a2x += lo_f(ue); a2y += hi_f(ue);
                a3x += lo_f(uf); a3y += hi_f(uf);
            }
            {   // final preloaded block of 16
                unsigned u0 = h1u[s0 * H1DW + lane];
                unsigned u1 = h1u[s1 * H1DW + lane];
                unsigned u2 = h1u[s2 * H1DW + lane];
                unsigned u3 = h1u[s3 * H1DW + lane];
                unsigned u4 = h1u[s4 * H1DW + lane];
                unsigned u5 = h1u[s5 * H1DW + lane];
                unsigned u6 = h1u[s6 * H1DW + lane];
                unsigned u7 = h1u[s7 * H1DW + lane];
                unsigned u8 = h1u[s8 * H1DW + lane];
                unsigned u9 = h1u[s9 * H1DW + lane];
                unsigned ua = h1u[sa * H1DW + lane];
                unsigned ub = h1u[sb * H1DW + lane];
                unsigned uc = h1u[sc * H1DW + lane];
                unsigned ud = h1u[sd * H1DW + lane];
                unsigned ue = h1u[se * H1DW + lane];
                unsigned uf = h1u[sf * H1DW + lane];
                a0x += lo_f(u0); a0y += hi_f(u0);
                a1x += lo_f(u1); a1y += hi_f(u1);
                a2x += lo_f(u2); a2y += hi_f(u2);
                a3x += lo_f(u3); a3y += hi_f(u3);
                a0x += lo_f(u4); a0y += hi_f(u4);
                a1x += lo_f(u5); a1y += hi_f(u5);
                a2x += lo_f(u6); a2y += hi_f(u6);
                a3x += lo_f(u7); a3y += hi_f(u7);
                a0x += lo_f(u8); a0y += hi_f(u8);
                a1x += lo_f(u9); a1y += hi_f(u9);
                a2x += lo_f(ua); a2y += hi_f(ua);
                a3x += lo_f(ub); a3y += hi_f(ub);
                a0x += lo_f(uc); a0y += hi_f(uc);
                a1x += lo_f(ud); a1y += hi_f(ud);
                a2x += lo_f(ue); a2y += hi_f(ue);
                a3x += lo_f(uf); a3y += hi_f(uf);
                e += 16;
            }
        }
        for (; e + 8 <= dg; e += 8) {
            int s0 = csr[st + e + 0], s1 = csr[st + e + 1];
            int s2 = csr[st + e + 2], s3 = csr[st + e + 3];
            int s4 = csr[st + e + 4], s5 = csr[st + e + 5];
            int s6 = csr[st + e + 6], s7 = csr[st + e + 7];
            unsigned u0 = h1u[s0 * H1DW + lane];
            unsigned u1 = h1u[s1 * H1DW + lane];
            unsigned u2 = h1u[s2 * H1DW + lane];
            unsigned u3 = h1u[s3 * H1DW + lane];
            unsigned u4 = h1u[s4 * H1DW + lane];
            unsigned u5 = h1u[s5 * H1DW + lane];
            unsigned u6 = h1u[s6 * H1DW + lane];
            unsigned u7 = h1u[s7 * H1DW + lane];
            a0x += lo_f(u0); a0y += hi_f(u0);
            a1x += lo_f(u1); a1y += hi_f(u1);
            a2x += lo_f(u2); a2y += hi_f(u2);
            a3x += lo_f(u3); a3y += hi_f(u3);
            a0x += lo_f(u4); a0y += hi_f(u4);
            a1x += lo_f(u5); a1y += hi_f(u5);
            a2x += lo_f(u6); a2y += hi_f(u6);
            a3x += lo_f(u7); a3y += hi_f(u7);
        }
        for (; e + 4 <= dg; e += 4) {
            int s0 = csr[st + e];
            int s1 = csr[st + e + 1];
            int s2 = csr[st + e + 2];
            int s3 = csr[st + e + 3];
            unsigned u0 = h1u[s0 * H1DW + lane];
            unsigned u1 = h1u[s1 * H1DW + lane];
            unsigned u2 = h1u[s2 * H1DW + lane];
            unsigned u3 = h1u[s3 * H1DW + lane];
            a0x += lo_f(u0); a0y += hi_f(u0);
            a1x += lo_f(u1); a1y += hi_f(u1);
            a2x += lo_f(u2); a2y += hi_f(u2);
            a3x += lo_f(u3); a3y += hi_f(u3);
        }
        for (; e < dg; e++) {
            unsigned u = h1u[csr[st + e] * H1DW + lane];
            a0x += lo_f(u); a0y += hi_f(u);
        }
        float sx = (a0x + a1x) + (a2x + a3x);
        float sy = (a0y + a1y) + (a2y + a3y);
        unsigned su = h1u[node * H1DW + lane];
        float di = dinv[node];
        float v0 = di * (sx + lo_f(su)) + b1[2 * lane];
        float v1 = di * (sy + hi_f(su)) + b1[2 * lane + 1];
        hl[g][2 * lane] = fmaxf(v0, 0.f);
        hl[g][2 * lane + 1] = fmaxf(v1, 0.f);
    }
    __syncthreads();
    if (t < 128) {
        int n2 = t >> 3;
        int op = t & 7;
        int node2 = blockIdx.x * 16 + n2;
        if (node2 < N) {
            float a0 = 0.f, a1 = 0.f;
#pragma unroll
            for (int k = 0; k < NHID; k++) {
                float hv = hl[n2][k];
                a0 += hv * w2s[k * NCLS + 2 * op];
                a1 += hv * w2s[k * NCLS + 2 * op + 1];
            }
            float di2 = dinv[node2];
            h2u[node2 * (NCLS / 2) + op] = pack2(di2 * a0, di2 * a1);
        }
    }
}

// K5: layer-2 pull aggregation + log_softmax (8 lanes x 2 feats; 3.2MB h2u
//     table L2-resident; 16-deep rotated gather pipeline).
__global__ void __launch_bounds__(256) agg2_kernel(const int* __restrict__ csr,
                                                   const int* __restrict__ rowst,
                                                   const ushort_t* __restrict__ degs,
                                                   const unsigned* __restrict__ h2u,
                                                   const float* __restrict__ dinv,
                                                   const float* __restrict__ b2,
                                                   float2* __restrict__ out2, int N) {
    int g = threadIdx.x >> 3;
    int lane = threadIdx.x & 7;
    int node = blockIdx.x * 32 + g;
    if (node >= N) return;
    int st = rowst[node];
    int dg = degs[node];
    float a0x = 0.f, a0y = 0.f, a1x = 0.f, a1y = 0.f;
    float a2x = 0.f, a2y = 0.f, a3x = 0.f, a3y = 0.f;
    int e = 0;
    if (dg >= 16) {
        int s0 = csr[st + 0],  s1 = csr[st + 1];
        int s2 = csr[st + 2],  s3 = csr[st + 3];
        int s4 = csr[st + 4],  s5 = csr[st + 5];
        int s6 = csr[st + 6],  s7 = csr[st + 7];
        int s8 = csr[st + 8],  s9 = csr[st + 9];
        int sa = csr[st + 10], sb = csr[st + 11];
        int sc = csr[st + 12], sd = csr[st + 13];
        int se = csr[st + 14], sf = csr[st + 15];
        for (; e + 32 <= dg; e += 16) {
            unsigned u0 = h2u[s0 * (NCLS / 2) + lane];
            unsigned u1 = h2u[s1 * (NCLS / 2) + lane];
            unsigned u2 = h2u[s2 * (NCLS / 2) + lane];
            unsigned u3 = h2u[s3 * (NCLS / 2) + lane];
            unsigned u4 = h2u[s4 * (NCLS / 2) + lane];
            unsigned u5 = h2u[s5 * (NCLS / 2) + lane];
            unsigned u6 = h2u[s6 * (NCLS / 2) + lane];
            unsigned u7 = h2u[s7 * (NCLS / 2) + lane];
            unsigned u8 = h2u[s8 * (NCLS / 2) + lane];
            unsigned u9 = h2u[s9 * (NCLS / 2) + lane];
            unsigned ua = h2u[sa * (NCLS / 2) + lane];
            unsigned ub = h2u[sb * (NCLS / 2) + lane];
            unsigned uc = h2u[sc * (NCLS / 2) + lane];
            unsigned ud = h2u[sd * (NCLS / 2) + lane];
            unsigned ue = h2u[se * (NCLS / 2) + lane];
            unsigned uf = h2u[sf * (NCLS / 2) + lane];
            s0 = csr[st + e + 16]; s1 = csr[st + e + 17];
            s2 = csr[st + e + 18]; s3 = csr[st + e + 19];
            s4 = csr[st + e + 20]; s5 = csr[st + e + 21];
            s6 = csr[st + e + 22]; s7 = csr[st + e + 23];
            s8 = csr[st + e + 24]; s9 = csr[st + e + 25];
            sa = csr[st + e + 26]; sb = csr[st + e + 27];
            sc = csr[st + e + 28]; sd = csr[st + e + 29];
            se = csr[st + e + 30]; sf = csr[st + e + 31];
            a0x += lo_f(u0); a0y += hi_f(u0);
            a1x += lo_f(u1); a1y += hi_f(u1);
            a2x += lo_f(u2); a2y += hi_f(u2);
            a3x += lo_f(u3); a3y += hi_f(u3);
            a0x += lo_f(u4); a0y += hi_f(u4);
            a1x += lo_f(u5); a1y += hi_f(u5);
            a2x += lo_f(u6); a2y += hi_f(u6);
            a3x += lo_f(u7); a3y += hi_f(u7);
            a0x += lo_f(u8); a0y += hi_f(u8);
            a1x += lo_f(u9); a1y += hi_f(u9);
            a2x += lo_f(ua); a2y += hi_f(ua);
            a3x += lo_f(ub); a3y += hi_f(ub);
            a0x += lo_f(uc); a0y += hi_f(uc);
            a1x += lo_f(ud); a1y += hi_f(ud);
            a2x += lo_f(ue); a2y += hi_f(ue);
            a3x += lo_f(uf); a3y += hi_f(uf);
        }
        {   // final preloaded block of 16
            unsigned u0 = h2u[s0 * (NCLS / 2) + lane];
            unsigned u1 = h2u[s1 * (NCLS / 2) + lane];
            unsigned u2 = h2u[s2 * (NCLS / 2) + lane];
            unsigned u3 = h2u[s3 * (NCLS / 2) + lane];
            unsigned u4 = h2u[s4 * (NCLS / 2) + lane];
            unsigned u5 = h2u[s5 * (NCLS / 2) + lane];
            unsigned u6 = h2u[s6 * (NCLS / 2) + lane];
            unsigned u7 = h2u[s7 * (NCLS / 2) + lane];
            unsigned u8 = h2u[s8 * (NCLS / 2) + lane];
            unsigned u9 = h2u[s9 * (NCLS / 2) + lane];
            unsigned ua = h2u[sa * (NCLS / 2) + lane];
            unsigned ub = h2u[sb * (NCLS / 2) + lane];
            unsigned uc = h2u[sc * (NCLS / 2) + lane];
            unsigned ud = h2u[sd * (NCLS / 2) + lane];
            unsigned ue = h2u[se * (NCLS / 2) + lane];
            unsigned uf = h2u[sf * (NCLS / 2) + lane];
            a0x += lo_f(u0); a0y += hi_f(u0);
            a1x += lo_f(u1); a1y += hi_f(u1);
            a2x += lo_f(u2); a2y += hi_f(u2);
            a3x += lo_f(u3); a3y += hi_f(u3);
            a0x += lo_f(u4); a0y += hi_f(u4);
            a1x += lo_f(u5); a1y += hi_f(u5);
            a2x += lo_f(u6); a2y += hi_f(u6);
            a3x += lo_f(u7); a3y += hi_f(u7);
            a0x += lo_f(u8); a0y += hi_f(u8);
            a1x += lo_f(u9); a1y += hi_f(u9);
            a2x += lo_f(ua); a2y += hi_f(ua);
            a3x += lo_f(ub); a3y += hi_f(ub);
            a0x += lo_f(uc); a0y += hi_f(uc);
            a1x += lo_f(ud); a1y += hi_f(ud);
            a2x += lo_f(ue); a2y += hi_f(ue);
            a3x += lo_f(uf); a3y += hi_f(uf);
            e += 16;
        }
    }
    for (; e + 8 <= dg; e += 8) {
        int s0 = csr[st + e + 0], s1 = csr[st + e + 1];
        int s2 = csr[st + e + 2], s3 = csr[st + e + 3];
        int s4 = csr[st + e + 4], s5 = csr[st + e + 5];
        int s6 = csr[st + e + 6], s7 = csr[st + e + 7];
        unsigned u0 = h2u[s0 * (NCLS / 2) + lane];
        unsigned u1 = h2u[s1 * (NCLS / 2) + lane];
        unsigned u2 = h2u[s2 * (NCLS / 2) + lane];
        unsigned u3 = h2u[s3 * (NCLS / 2) + lane];
        unsigned u4 = h2u[s4 * (NCLS / 2) + lane];
        unsigned u5 = h2u[s5 * (NCLS / 2) + lane];
        unsigned u6 = h2u[s6 * (NCLS / 2) + lane];
        unsigned u7 = h2u[s7 * (NCLS / 2) + lane];
        a0x += lo_f(u0); a0y += hi_f(u0);
        a1x += lo_f(u1); a1y += hi_f(u1);
        a2x += lo_f(u2); a2y += hi_f(u2);
        a3x += lo_f(u3); a3y += hi_f(u3);
        a0x += lo_f(u4); a0y += hi_f(u4);
        a1x += lo_f(u5); a1y += hi_f(u5);
        a2x += lo_f(u6); a2y += hi_f(u6);
        a3x += lo_f(u7); a3y += hi_f(u7);
    }
    for (; e + 4 <= dg; e += 4) {
        int s0 = csr[st + e];
        int s1 = csr[st + e + 1];
        int s2 = csr[st + e + 2];
        int s3 = csr[st + e + 3];
        unsigned u0 = h2u[s0 * (NCLS / 2) + lane];
        unsigned u1 = h2u[s1 * (NCLS / 2) + lane];
        unsigned u2 = h2u[s2 * (NCLS / 2) + lane];
        unsigned u3 = h2u[s3 * (NCLS / 2) + lane];
        a0x += lo_f(u0); a0y += hi_f(u0);
        a1x += lo_f(u1); a1y += hi_f(u1);
        a2x += lo_f(u2); a2y += hi_f(u2);
        a3x += lo_f(u3); a3y += hi_f(u3);
    }
    for (; e < dg; e++) {
        unsigned u = h2u[csr[st + e] * (NCLS / 2) + lane];
        a0x += lo_f(u); a0y += hi_f(u);
    }
    float sx = (a0x + a1x) + (a2x + a3x);
    float sy = (a0y + a1y) + (a2y + a3y);
    unsigned su = h2u[node * (NCLS / 2) + lane];
    float di = dinv[node];
    float l0 = di * (sx + lo_f(su)) + b2[2 * lane];
    float l1 = di * (sy + hi_f(su)) + b2[2 * lane + 1];
    float m = fmaxf(l0, l1);
#pragma unroll
    for (int o = 1; o < 8; o <<= 1) m = fmaxf(m, __shfl_xor(m, o, 8));
    float ssum = expf(l0 - m) + expf(l1 - m);
#pragma unroll
    for (int o = 1; o < 8; o <<= 1) ssum += __shfl_xor(ssum, o, 8);
    float ls = logf(ssum) + m;
    out2[node * 8 + lane] = make_float2(l0 - ls, l1 - ls);
}

extern "C" void kernel_launch(void* const* d_in, const int* in_sizes, int n_in,
                              void* d_out, int out_size, void* d_ws, size_t ws_size,
                              hipStream_t stream) {
    const float* x  = (const float*)d_in[0];
    const int*   ei = (const int*)d_in[1];
    const float* W1 = (const float*)d_in[2];
    const float* b1 = (const float*)d_in[3];
    const float* W2 = (const float*)d_in[4];
    const float* b2 = (const float*)d_in[5];
    float* out = (float*)d_out;

    const int N = in_sizes[0] / NFEAT;        // 100000
    const int E = in_sizes[1] / 2;            // 3200000
    const int NBUCK = (N + BKN - 1) >> NBSH;  // 391

    // workspace: [wpk 16KB][gcur 512*GSTR][rowst N][degs N ushort][dinv N]
    // then 64B-aligned [csr NBUCK*CAP][part NBUCK*CAP][h1u N*48B dense];
    // h2u aliases part.
    bf16x8_t* wpk = (bf16x8_t*)d_ws;          // 16 KB
    int* gcur  = (int*)((char*)d_ws + 16384);
    int* rowst = gcur + 512 * GSTR;
    ushort_t* degs = (ushort_t*)(rowst + N);
    float* dinv = (float*)(degs + ((N + 1) & ~1));
    size_t off = (size_t)((char*)(dinv + N) - (char*)d_ws);
    off = (off + 63) & ~(size_t)63;
    int* csr = (int*)((char*)d_ws + off);
    size_t off2 = off + (size_t)NBUCK * CAP * 4;
    int* part = (int*)((char*)d_ws + off2);
    unsigned* h2u = (unsigned*)part;          // alias: part dead after csr_kernel
    size_t off3 = off2 + (size_t)NBUCK * CAP * 4;
    unsigned* h1u = (unsigned*)((char*)d_ws + off3);   // 4.8 MB dense

    wprep_kernel<<<1, 64, 0, stream>>>(W1, wpk, gcur);
    part1_kernel<<<(E + TILE - 1) / TILE, PT, 0, stream>>>(ei, gcur, part, E);
    csr_kernel<<<NBUCK, 1024, 0, stream>>>(part, gcur, csr, rowst, degs, dinv, NBUCK, N);
    const int ntile = (N + 15) / 16;
    gemm1_kernel<<<(ntile * 64 + 255) / 256, 256, 0, stream>>>(x, wpk, dinv, h1u, N);
    agg1_kernel<<<(N + 15) / 16, 192, 0, stream>>>(csr, rowst, degs, h1u,
                                                   dinv, b1, W2, h2u, N);
    agg2_kernel<<<(N + 31) / 32, 256, 0, stream>>>(csr, rowst, degs, h2u,
                                                   dinv, b2, (float2*)out, N);
}

// Round 12
// 213.004 us; speedup vs baseline: 1.0254x; 1.0254x over previous
//
#include <hip/hip_runtime.h>
#include <math.h>

#define NFEAT 128
#define NHID  24
#define NCLS  16
#define H1DW  12                // h1 row = 24 bf16 = 12 dwords = 48B DENSE (no pad).
                                // 4.8MB footprint vs 4MB/XCD L2 (r10: -3.6us vs padded)
#define NBSH  8                 // 256 nodes per bucket
#define BKN   256
#define QSH   15                // src-quarter shift (sub-sort key for L2 phasing)
#define CAP   9216              // fixed slots per bucket (mean 8192, sigma~90: +11 sigma)
#define TILE  8192              // edges per partition tile
#define PT    1024              // partition block threads
#define EPT   (TILE / PT)       // 8 edges per thread
#define GSTR  16                // gcur stride in ints: one counter per 64B line

typedef unsigned short ushort_t;
typedef __attribute__((ext_vector_type(8))) short bf16x8_t;
typedef __attribute__((ext_vector_type(4))) float f32x4_t;

__device__ __forceinline__ ushort_t f2bf(float f) {
    unsigned x; __builtin_memcpy(&x, &f, 4);
    unsigned r = (x + 0x7FFF + ((x >> 16) & 1)) >> 16;   // RNE
    return (ushort_t)r;
}
__device__ __forceinline__ float bf2f(ushort_t h) {
    unsigned x = ((unsigned)h) << 16;
    float f; __builtin_memcpy(&f, &x, 4); return f;
}
__device__ __forceinline__ float lo_f(unsigned u) {
    unsigned x = u << 16;
    float f; __builtin_memcpy(&f, &x, 4); return f;
}
__device__ __forceinline__ float hi_f(unsigned u) {
    unsigned x = u & 0xFFFF0000u;
    float f; __builtin_memcpy(&f, &x, 4); return f;
}
__device__ __forceinline__ unsigned pack2(float a, float b) {
    return (unsigned)f2bf(a) | ((unsigned)f2bf(b) << 16);
}

// ---------------------------------------------------------------------------
// K0: one-wave W1 fragment prep (hi/lo bf16 split, prepacked) + gcur zero.
__global__ void __launch_bounds__(64) wprep_kernel(const float* __restrict__ W1,
                                                   bf16x8_t* __restrict__ wpk,
                                                   int* __restrict__ gcur) {
    int l = threadIdx.x;
    for (int i = l; i < 512; i += 64) gcur[i * GSTR] = 0;
    int mrow = l & 15;
    int kgrp = l >> 4;
#pragma unroll
    for (int ct = 0; ct < 2; ct++) {
        int n = ct * 16 + mrow;
        bool nv = (n < NHID);
#pragma unroll
        for (int kb = 0; kb < 4; kb++) {
            bf16x8_t hi, lo;
#pragma unroll
            for (int j = 0; j < 8; j++) {
                int k = kb * 32 + kgrp * 8 + j;
                float w = nv ? W1[k * NHID + n] : 0.0f;
                ushort_t h = f2bf(w);
                hi[j] = (short)h;
                lo[j] = (short)f2bf(w - bf2f(h));
            }
            int f = ct * 4 + kb;
            wpk[(f * 2 + 0) * 64 + l] = hi;
            wpk[(f * 2 + 1) * 64 + l] = lo;
        }
    }
}

// ---------------------------------------------------------------------------
// K1: LDS-staged partition into fixed-capacity bucket regions.
__global__ void __launch_bounds__(1024) part1_kernel(const int* __restrict__ ei,
                                                     int* __restrict__ gcur,
                                                     int* __restrict__ part, int E) {
    __shared__ int stage[TILE];        // 32 KB
    __shared__ ushort_t sbkt[TILE];    // 16 KB
    __shared__ int lh[512];            // hist -> cursor
    __shared__ int lofs[512];
    __shared__ int gbase[512];
    __shared__ int wsum[8];
    int t = threadIdx.x;
    int e0 = blockIdx.x * TILE;
    int cnt = min(TILE, E - e0);
    if (t < 512) lh[t] = 0;
    __syncthreads();
    int dstv[EPT];
#pragma unroll
    for (int r = 0; r < EPT; r++) {
        int i = t + r * PT;
        if (i < cnt) {
            int d = ei[e0 + i];
            dstv[r] = d;
            atomicAdd(&lh[d >> NBSH], 1);
        }
    }
    __syncthreads();
    int v = 0, s = 0;
    if (t < 512) {
        v = lh[t];
        s = v;
#pragma unroll
        for (int o = 1; o < 64; o <<= 1) {
            int u = __shfl_up(s, o, 64);
            if ((t & 63) >= o) s += u;
        }
        if ((t & 63) == 63) wsum[t >> 6] = s;
    }
    __syncthreads();
    if (t < 8) {
        int w = wsum[t];
        int ss = w;
#pragma unroll
        for (int o = 1; o < 8; o <<= 1) {
            int u = __shfl_up(ss, o, 8);
            if (t >= o) ss += u;
        }
        wsum[t] = ss - w;   // exclusive
    }
    __syncthreads();
    if (t < 512) {
        int ex = s + wsum[t >> 6] - v;
        lofs[t] = ex;
        gbase[t] = v ? (t * CAP + atomicAdd(&gcur[t * GSTR], v)) : 0;
        lh[t] = ex;   // cursor
    }
    __syncthreads();
#pragma unroll
    for (int r = 0; r < EPT; r++) {
        int i = t + r * PT;
        if (i < cnt) {
            int dst = dstv[r];
            int src = ei[E + e0 + i];
            int b = dst >> NBSH;
            int p = atomicAdd(&lh[b], 1);
            stage[p] = ((dst & (BKN - 1)) << 17) | src;
            sbkt[p] = (ushort_t)b;
        }
    }
    __syncthreads();
#pragma unroll
    for (int r = 0; r < EPT; r++) {
        int i = t + r * PT;
        if (i < cnt) {
            int b = sbkt[i];
            part[gbase[b] + (i - lofs[b])] = stage[i];
        }
    }
}

// K2: per-bucket CSR build, register-stashed single global pass. (~17.4us, r8)
__global__ void __launch_bounds__(1024) csr_kernel(const int* __restrict__ part,
                                                   const int* __restrict__ gcur,
                                                   int* __restrict__ csr,
                                                   int* __restrict__ rowst,
                                                   ushort_t* __restrict__ degs,
                                                   float* __restrict__ dinv,
                                                   int NBUCK, int N) {
    __shared__ int h[1024];
    __shared__ int cur[1024];
    __shared__ int wsum[16];
    int b = blockIdx.x, t = threadIdx.x;
    int st = b * CAP;
    int cnt = gcur[b * GSTR];          // <= CAP = 9216 = 9*1024
    h[t] = 0;
    __syncthreads();
    int r[9];
#pragma unroll
    for (int i = 0; i < 9; i++) {
        int idx = t + (i << 10);
        if (idx < cnt) {
            int ent = part[st + idx];
            r[i] = ent;
            atomicAdd(&h[((ent >> 17) << 2) | ((ent & 0x1FFFF) >> QSH)], 1);
        }
    }
    __syncthreads();
    int v = h[t];
    if ((t & 3) == 0) {
        int node = (b << NBSH) + (t >> 2);
        if (node < N) {
            int dg = h[t] + h[t + 1] + h[t + 2] + h[t + 3];
            dinv[node] = rsqrtf((float)dg + 1.0f);
            degs[node] = (ushort_t)dg;
        }
    }
    int s = v;
#pragma unroll
    for (int o = 1; o < 64; o <<= 1) {
        int u = __shfl_up(s, o, 64);
        if ((t & 63) >= o) s += u;
    }
    if ((t & 63) == 63) wsum[t >> 6] = s;
    __syncthreads();
    if (t < 16) {
        int w = wsum[t];
        int ss = w;
#pragma unroll
        for (int o = 1; o < 16; o <<= 1) {
            int u = __shfl_up(ss, o, 16);
            if (t >= o) ss += u;
        }
        wsum[t] = ss - w;
    }
    __syncthreads();
    int ex = s + wsum[t >> 6] - v;
    if ((t & 3) == 0) {
        int node = (b << NBSH) + (t >> 2);
        if (node < N) rowst[node] = st + ex;
    }
    cur[t] = ex;
    __syncthreads();
#pragma unroll
    for (int i = 0; i < 9; i++) {
        int idx = t + (i << 10);
        if (idx < cnt) {
            int ent = r[i];
            int src = ent & 0x1FFFF;
            int p = atomicAdd(&cur[((ent >> 17) << 2) | (src >> QSH)], 1);
            csr[st + p] = src;
        }
    }
}

// K3: h1(bf16, DENSE stride 24) = dinv[row] * (x @ W1), via MFMA. Prepacked
//     W1 fragments; 3-term bf16 split for f32 accuracy.
__global__ void __launch_bounds__(256) gemm1_kernel(const float* __restrict__ x,
                                                    const bf16x8_t* __restrict__ wpk,
                                                    const float* __restrict__ dinv,
                                                    unsigned* __restrict__ h1u, int N) {
    int gw = (blockIdx.x * 256 + threadIdx.x) >> 6;   // global wave id = row tile
    int l = threadIdx.x & 63;
    int ntile = (N + 15) >> 4;
    if (gw >= ntile) return;
    int mrow = l & 15;
    int kgrp = l >> 4;          // 0..3

    bf16x8_t whi[2][4], wlo[2][4];
#pragma unroll
    for (int ct = 0; ct < 2; ct++) {
#pragma unroll
        for (int kb = 0; kb < 4; kb++) {
            int f = ct * 4 + kb;
            whi[ct][kb] = wpk[(f * 2 + 0) * 64 + l];
            wlo[ct][kb] = wpk[(f * 2 + 1) * 64 + l];
        }
    }

    int row0 = gw * 16;
    int xrow = row0 + mrow;
    if (xrow >= N) xrow = N - 1;
    const float* xp = x + (size_t)xrow * NFEAT + kgrp * 8;

    f32x4_t acc0 = {0.f, 0.f, 0.f, 0.f};
    f32x4_t acc1 = {0.f, 0.f, 0.f, 0.f};
#pragma unroll
    for (int kb = 0; kb < 4; kb++) {
        float4 fa = *(const float4*)(xp + kb * 32);
        float4 fb = *(const float4*)(xp + kb * 32 + 4);
        float f[8] = {fa.x, fa.y, fa.z, fa.w, fb.x, fb.y, fb.z, fb.w};
        bf16x8_t ah, al;
#pragma unroll
        for (int j = 0; j < 8; j++) {
            ushort_t h = f2bf(f[j]);
            ah[j] = (short)h;
            al[j] = (short)f2bf(f[j] - bf2f(h));
        }
        acc0 = __builtin_amdgcn_mfma_f32_16x16x32_bf16(ah, whi[0][kb], acc0, 0, 0, 0);
        acc0 = __builtin_amdgcn_mfma_f32_16x16x32_bf16(ah, wlo[0][kb], acc0, 0, 0, 0);
        acc0 = __builtin_amdgcn_mfma_f32_16x16x32_bf16(al, whi[0][kb], acc0, 0, 0, 0);
        acc1 = __builtin_amdgcn_mfma_f32_16x16x32_bf16(ah, whi[1][kb], acc1, 0, 0, 0);
        acc1 = __builtin_amdgcn_mfma_f32_16x16x32_bf16(ah, wlo[1][kb], acc1, 0, 0, 0);
        acc1 = __builtin_amdgcn_mfma_f32_16x16x32_bf16(al, whi[1][kb], acc1, 0, 0, 0);
    }

    ushort_t* hs = (ushort_t*)h1u;
#pragma unroll
    for (int r = 0; r < 4; r++) {
        int row = row0 + kgrp * 4 + r;
        if (row < N) {
            float di = dinv[row];
            hs[(size_t)row * (2 * H1DW) + mrow] = f2bf(di * acc0[r]);
            if (mrow < NHID - 16)
                hs[(size_t)row * (2 * H1DW) + 16 + mrow] = f2bf(di * acc1[r]);
        }
    }
}

// K4: layer-1 pull aggregation + FUSED layer-2 dense transform.
//     12 lanes x 2 feats per node; dense 48B h1 rows; 8-deep rotated gather
//     pipeline (depth-8 is the measured optimum: r3 +15%, r11 16-deep -2.5%).
__global__ void __launch_bounds__(192) agg1_kernel(const int* __restrict__ csr,
                                                   const int* __restrict__ rowst,
                                                   const ushort_t* __restrict__ degs,
                                                   const unsigned* __restrict__ h1u,
                                                   const float* __restrict__ dinv,
                                                   const float* __restrict__ b1,
                                                   const float* __restrict__ W2,
                                                   unsigned* __restrict__ h2u, int N) {
    __shared__ float hl[16][25];          // +1 pad
    __shared__ float w2s[NHID * NCLS];
    int t = threadIdx.x;
    for (int i = t; i < NHID * NCLS; i += 192) w2s[i] = W2[i];
    int g = t / 12;
    int lane = t - g * 12;
    int node = blockIdx.x * 16 + g;
    if (node < N) {
        int st = rowst[node];
        int dg = degs[node];
        float a0x = 0.f, a0y = 0.f, a1x = 0.f, a1y = 0.f;
        float a2x = 0.f, a2y = 0.f, a3x = 0.f, a3y = 0.f;
        int e = 0;
        if (dg >= 8) {
            int s0 = csr[st];     int s1 = csr[st + 1];
            int s2 = csr[st + 2]; int s3 = csr[st + 3];
            int s4 = csr[st + 4]; int s5 = csr[st + 5];
            int s6 = csr[st + 6]; int s7 = csr[st + 7];
            for (; e + 16 <= dg; e += 8) {
                unsigned u0 = h1u[s0 * H1DW + lane];
                unsigned u1 = h1u[s1 * H1DW + lane];
                unsigned u2 = h1u[s2 * H1DW + lane];
                unsigned u3 = h1u[s3 * H1DW + lane];
                unsigned u4 = h1u[s4 * H1DW + lane];
                unsigned u5 = h1u[s5 * H1DW + lane];
                unsigned u6 = h1u[s6 * H1DW + lane];
                unsigned u7 = h1u[s7 * H1DW + lane];
                s0 = csr[st + e + 8];  s1 = csr[st + e + 9];
                s2 = csr[st + e + 10]; s3 = csr[st + e + 11];
                s4 = csr[st + e + 12]; s5 = csr[st + e + 13];
                s6 = csr[st + e + 14]; s7 = csr[st + e + 15];
                a0x += lo_f(u0); a0y += hi_f(u0);
                a1x += lo_f(u1); a1y += hi_f(u1);
                a2x += lo_f(u2); a2y += hi_f(u2);
                a3x += lo_f(u3); a3y += hi_f(u3);
                a0x += lo_f(u4); a0y += hi_f(u4);
                a1x += lo_f(u5); a1y += hi_f(u5);
                a2x += lo_f(u6); a2y += hi_f(u6);
                a3x += lo_f(u7); a3y += hi_f(u7);
            }
            {   // final preloaded block
                unsigned u0 = h1u[s0 * H1DW + lane];
                unsigned u1 = h1u[s1 * H1DW + lane];
                unsigned u2 = h1u[s2 * H1DW + lane];
                unsigned u3 = h1u[s3 * H1DW + lane];
                unsigned u4 = h1u[s4 * H1DW + lane];
                unsigned u5 = h1u[s5 * H1DW + lane];
                unsigned u6 = h1u[s6 * H1DW + lane];
                unsigned u7 = h1u[s7 * H1DW + lane];
                a0x += lo_f(u0); a0y += hi_f(u0);
                a1x += lo_f(u1); a1y += hi_f(u1);
                a2x += lo_f(u2); a2y += hi_f(u2);
                a3x += lo_f(u3); a3y += hi_f(u3);
                a0x += lo_f(u4); a0y += hi_f(u4);
                a1x += lo_f(u5); a1y += hi_f(u5);
                a2x += lo_f(u6); a2y += hi_f(u6);
                a3x += lo_f(u7); a3y += hi_f(u7);
                e += 8;
            }
        }
        for (; e + 4 <= dg; e += 4) {
            int s0 = csr[st + e];
            int s1 = csr[st + e + 1];
            int s2 = csr[st + e + 2];
            int s3 = csr[st + e + 3];
            unsigned u0 = h1u[s0 * H1DW + lane];
            unsigned u1 = h1u[s1 * H1DW + lane];
            unsigned u2 = h1u[s2 * H1DW + lane];
            unsigned u3 = h1u[s3 * H1DW + lane];
            a0x += lo_f(u0); a0y += hi_f(u0);
            a1x += lo_f(u1); a1y += hi_f(u1);
            a2x += lo_f(u2); a2y += hi_f(u2);
            a3x += lo_f(u3); a3y += hi_f(u3);
        }
        for (; e < dg; e++) {
            unsigned u = h1u[csr[st + e] * H1DW + lane];
            a0x += lo_f(u); a0y += hi_f(u);
        }
        float sx = (a0x + a1x) + (a2x + a3x);
        float sy = (a0y + a1y) + (a2y + a3y);
        unsigned su = h1u[node * H1DW + lane];
        float di = dinv[node];
        float v0 = di * (sx + lo_f(su)) + b1[2 * lane];
        float v1 = di * (sy + hi_f(su)) + b1[2 * lane + 1];
        hl[g][2 * lane] = fmaxf(v0, 0.f);
        hl[g][2 * lane + 1] = fmaxf(v1, 0.f);
    }
    __syncthreads();
    if (t < 128) {
        int n2 = t >> 3;
        int op = t & 7;
        int node2 = blockIdx.x * 16 + n2;
        if (node2 < N) {
            float a0 = 0.f, a1 = 0.f;
#pragma unroll
            for (int k = 0; k < NHID; k++) {
                float hv = hl[n2][k];
                a0 += hv * w2s[k * NCLS + 2 * op];
                a1 += hv * w2s[k * NCLS + 2 * op + 1];
            }
            float di2 = dinv[node2];
            h2u[node2 * (NCLS / 2) + op] = pack2(di2 * a0, di2 * a1);
        }
    }
}

// K5: layer-2 pull aggregation + log_softmax (8 lanes x 2 feats; 3.2MB h2u
//     table L2-resident; 8-deep rotated gather pipeline).
__global__ void __launch_bounds__(256) agg2_kernel(const int* __restrict__ csr,
                                                   const int* __restrict__ rowst,
                                                   const ushort_t* __restrict__ degs,
                                                   const unsigned* __restrict__ h2u,
                                                   const float* __restrict__ dinv,
                                                   const float* __restrict__ b2,
                                                   float2* __restrict__ out2, int N) {
    int g = threadIdx.x >> 3;
    int lane = threadIdx.x & 7;
    int node = blockIdx.x * 32 + g;
    if (node >= N) return;
    int st = rowst[node];
    int dg = degs[node];
    float a0x = 0.f, a0y = 0.f, a1x = 0.f, a1y = 0.f;
    float a2x = 0.f, a2y = 0.f, a3x = 0.f, a3y = 0.f;
    int e = 0;
    if (dg >= 8) {
        int s0 = csr[st];     int s1 = csr[st + 1];
        int s2 = csr[st + 2]; int s3 = csr[st + 3];
        int s4 = csr[st + 4]; int s5 = csr[st + 5];
        int s6 = csr[st + 6]; int s7 = csr[st + 7];
        for (; e + 16 <= dg; e += 8) {
            unsigned u0 = h2u[s0 * (NCLS / 2) + lane];
            unsigned u1 = h2u[s1 * (NCLS / 2) + lane];
            unsigned u2 = h2u[s2 * (NCLS / 2) + lane];
            unsigned u3 = h2u[s3 * (NCLS / 2) + lane];
            unsigned u4 = h2u[s4 * (NCLS / 2) + lane];
            unsigned u5 = h2u[s5 * (NCLS / 2) + lane];
            unsigned u6 = h2u[s6 * (NCLS / 2) + lane];
            unsigned u7 = h2u[s7 * (NCLS / 2) + lane];
            s0 = csr[st + e + 8];  s1 = csr[st + e + 9];
            s2 = csr[st + e + 10]; s3 = csr[st + e + 11];
            s4 = csr[st + e + 12]; s5 = csr[st + e + 13];
            s6 = csr[st + e + 14]; s7 = csr[st + e + 15];
            a0x += lo_f(u0); a0y += hi_f(u0);
            a1x += lo_f(u1); a1y += hi_f(u1);
            a2x += lo_f(u2); a2y += hi_f(u2);
            a3x += lo_f(u3); a3y += hi_f(u3);
            a0x += lo_f(u4); a0y += hi_f(u4);
            a1x += lo_f(u5); a1y += hi_f(u5);
            a2x += lo_f(u6); a2y += hi_f(u6);
            a3x += lo_f(u7); a3y += hi_f(u7);
        }
        {   // final preloaded block
            unsigned u0 = h2u[s0 * (NCLS / 2) + lane];
            unsigned u1 = h2u[s1 * (NCLS / 2) + lane];
            unsigned u2 = h2u[s2 * (NCLS / 2) + lane];
            unsigned u3 = h2u[s3 * (NCLS / 2) + lane];
            unsigned u4 = h2u[s4 * (NCLS / 2) + lane];
            unsigned u5 = h2u[s5 * (NCLS / 2) + lane];
            unsigned u6 = h2u[s6 * (NCLS / 2) + lane];
            unsigned u7 = h2u[s7 * (NCLS / 2) + lane];
            a0x += lo_f(u0); a0y += hi_f(u0);
            a1x += lo_f(u1); a1y += hi_f(u1);
            a2x += lo_f(u2); a2y += hi_f(u2);
            a3x += lo_f(u3); a3y += hi_f(u3);
            a0x += lo_f(u4); a0y += hi_f(u4);
            a1x += lo_f(u5); a1y += hi_f(u5);
            a2x += lo_f(u6); a2y += hi_f(u6);
            a3x += lo_f(u7); a3y += hi_f(u7);
            e += 8;
        }
    }
    for (; e + 4 <= dg; e += 4) {
        int s0 = csr[st + e];
        int s1 = csr[st + e + 1];
        int s2 = csr[st + e + 2];
        int s3 = csr[st + e + 3];
        unsigned u0 = h2u[s0 * (NCLS / 2) + lane];
        unsigned u1 = h2u[s1 * (NCLS / 2) + lane];
        unsigned u2 = h2u[s2 * (NCLS / 2) + lane];
        unsigned u3 = h2u[s3 * (NCLS / 2) + lane];
        a0x += lo_f(u0); a0y += hi_f(u0);
        a1x += lo_f(u1); a1y += hi_f(u1);
        a2x += lo_f(u2); a2y += hi_f(u2);
        a3x += lo_f(u3); a3y += hi_f(u3);
    }
    for (; e < dg; e++) {
        unsigned u = h2u[csr[st + e] * (NCLS / 2) + lane];
        a0x += lo_f(u); a0y += hi_f(u);
    }
    float sx = (a0x + a1x) + (a2x + a3x);
    float sy = (a0y + a1y) + (a2y + a3y);
    unsigned su = h2u[node * (NCLS / 2) + lane];
    float di = dinv[node];
    float l0 = di * (sx + lo_f(su)) + b2[2 * lane];
    float l1 = di * (sy + hi_f(su)) + b2[2 * lane + 1];
    float m = fmaxf(l0, l1);
#pragma unroll
    for (int o = 1; o < 8; o <<= 1) m = fmaxf(m, __shfl_xor(m, o, 8));
    float ssum = expf(l0 - m) + expf(l1 - m);
#pragma unroll
    for (int o = 1; o < 8; o <<= 1) ssum += __shfl_xor(ssum, o, 8);
    float ls = logf(ssum) + m;
    out2[node * 8 + lane] = make_float2(l0 - ls, l1 - ls);
}

extern "C" void kernel_launch(void* const* d_in, const int* in_sizes, int n_in,
                              void* d_out, int out_size, void* d_ws, size_t ws_size,
                              hipStream_t stream) {
    const float* x  = (const float*)d_in[0];
    const int*   ei = (const int*)d_in[1];
    const float* W1 = (const float*)d_in[2];
    const float* b1 = (const float*)d_in[3];
    const float* W2 = (const float*)d_in[4];
    const float* b2 = (const float*)d_in[5];
    float* out = (float*)d_out;

    const int N = in_sizes[0] / NFEAT;        // 100000
    const int E = in_sizes[1] / 2;            // 3200000
    const int NBUCK = (N + BKN - 1) >> NBSH;  // 391

    // workspace: [wpk 16KB][gcur 512*GSTR][rowst N][degs N ushort][dinv N]
    // then 64B-aligned [csr NBUCK*CAP][part NBUCK*CAP][h1u N*48B dense];
    // h2u aliases part.
    bf16x8_t* wpk = (bf16x8_t*)d_ws;          // 16 KB
    int* gcur  = (int*)((char*)d_ws + 16384);
    int* rowst = gcur + 512 * GSTR;
    ushort_t* degs = (ushort_t*)(rowst + N);
    float* dinv = (float*)(degs + ((N + 1) & ~1));
    size_t off = (size_t)((char*)(dinv + N) - (char*)d_ws);
    off = (off + 63) & ~(size_t)63;
    int* csr = (int*)((char*)d_ws + off);
    size_t off2 = off + (size_t)NBUCK * CAP * 4;
    int* part = (int*)((char*)d_ws + off2);
    unsigned* h2u = (unsigned*)part;          // alias: part dead after csr_kernel
    size_t off3 = off2 + (size_t)NBUCK * CAP * 4;
    unsigned* h1u = (unsigned*)((char*)d_ws + off3);   // 4.8 MB dense

    wprep_kernel<<<1, 64, 0, stream>>>(W1, wpk, gcur);
    part1_kernel<<<(E + TILE - 1) / TILE, PT, 0, stream>>>(ei, gcur, part, E);
    csr_kernel<<<NBUCK, 1024, 0, stream>>>(part, gcur, csr, rowst, degs, dinv, NBUCK, N);
    const int ntile = (N + 15) / 16;
    gemm1_kernel<<<(ntile * 64 + 255) / 256, 256, 0, stream>>>(x, wpk, dinv, h1u, N);
    agg1_kernel<<<(N + 15) / 16, 192, 0, stream>>>(csr, rowst, degs, h1u,
                                                   dinv, b1, W2, h2u, N);
    agg2_kernel<<<(N + 31) / 32, 256, 0, stream>>>(csr, rowst, degs, h2u,
                                                   dinv, b2, (float2*)out, N);
}